// Round 6
// baseline (98.863 us; speedup 1.0000x reference)
//
#include <hip/hip_runtime.h>
#include <stdint.h>

typedef float f32x16 __attribute__((ext_vector_type(16)));
typedef long long2v __attribute__((ext_vector_type(2)));

#define BDIM 8192
// fp8 matrices stored fragment-major: byte(row, k) at
//   row*128 + ((k>>3)&1)*64 + (k>>4)*8 + (k&7)
// so one lane's A/B operand run for all of K=128 (fixed fh = (k>>3)&1) is a
// contiguous 64 B at row*128 + fh*64. One matrix = 1 MB.

// fp32 [8192,128] -> fp8 e4m3 fragment-major + fp32 row sum-of-squares.
// grid (512, 2): 16 rows/block. Thread: jg = lane&15 handles floats 8jg..8jg+7,
// which land in one contiguous 8-B dest: r*128 + (jg&1)*64 + (jg>>1)*8.
__global__ __launch_bounds__(256) void prep_kernel(const float* __restrict__ out_f,
                                                   const float* __restrict__ tgt_f,
                                                   uint8_t* __restrict__ ak,
                                                   float* __restrict__ xxyy) {
    const float* src = blockIdx.y ? tgt_f : out_f;
    uint8_t* dst = ak + (size_t)blockIdx.y * (1u << 20);
    float* nrm = xxyy + (size_t)blockIdx.y * BDIM;

    const int tid = threadIdx.x;
    const int lane = tid & 63;
    const int w = tid >> 6;
    const int jg = lane & 15;
    const int r = blockIdx.x * 16 + w * 4 + (lane >> 4);

    const float4* s4 = (const float4*)(src + (size_t)r * 128 + jg * 8);
    float4 a = s4[0], b = s4[1];

    uint32_t w0 = __builtin_amdgcn_cvt_pk_fp8_f32(a.x, a.y, 0, false);
    w0 = __builtin_amdgcn_cvt_pk_fp8_f32(a.z, a.w, w0, true);
    uint32_t w1 = __builtin_amdgcn_cvt_pk_fp8_f32(b.x, b.y, 0, false);
    w1 = __builtin_amdgcn_cvt_pk_fp8_f32(b.z, b.w, w1, true);
    *(uint2*)(dst + r * 128 + (jg & 1) * 64 + (jg >> 1) * 8) = make_uint2(w0, w1);

    float sq = a.x*a.x + a.y*a.y + a.z*a.z + a.w*a.w
             + b.x*b.x + b.y*b.y + b.z*b.z + b.w*b.w;
    sq += __shfl_xor(sq, 1); sq += __shfl_xor(sq, 2);
    sq += __shfl_xor(sq, 4); sq += __shfl_xor(sq, 8);   // reduce over the 16 jg-lanes
    if (jg == 0) nrm[r] = sq;
}

// 128x128 tile per block; C = A * B^T via mfma 32x32x16 fp8_fp8.
// NO LDS tile staging: operands load straight from global (L2-resident, 2 MB
// total input) as global_load_dwordx4 — 16 loads/wave for the whole tile.
// Barriers: one after xxl/yyl fill, one before the wsum combine. No drains.
__global__ __launch_bounds__(256, 4) void dist_kernel(const uint8_t* __restrict__ Ak,
                                                      const uint8_t* __restrict__ Bk,
                                                      const float* __restrict__ xxg,
                                                      const float* __restrict__ yyg,
                                                      float* __restrict__ partials) {
    __shared__ float xxl[128];
    __shared__ float yyl[128];
    __shared__ float wsum[4];

    const int tid = threadIdx.x;
    const int lane = tid & 63;
    const int wid = tid >> 6;
    const int wr = wid >> 1, wc = wid & 1;      // 2x2 wave grid, each wave 64x64
    const int bx = blockIdx.x, by = blockIdx.y;

    if (tid < 128) xxl[tid] = xxg[bx * 128 + tid];
    else           yyl[tid - 128] = yyg[by * 128 + (tid - 128)];
    __syncthreads();

    const int lm = lane & 31;                   // fragment row/col within 32
    const int fh = lane >> 5;                   // k-half within a 16-k step
    const uint8_t* arow = Ak + ((size_t)(bx * 128 + wr * 64 + lm) << 7) + (fh << 6);
    const uint8_t* brow = Bk + ((size_t)(by * 128 + wc * 64 + lm) << 7) + (fh << 6);

    f32x16 acc[2][2] = {};
    #pragma unroll
    for (int h = 0; h < 2; ++h) {               // two K-halves of 64
        long2v av[2][2], bv[2][2];              // [t = row strip][u = s-pair]
        #pragma unroll
        for (int t = 0; t < 2; ++t) {
            #pragma unroll
            for (int u = 0; u < 2; ++u) {
                av[t][u] = *(const long2v*)(arow + t * 4096 + h * 32 + u * 16);
                bv[t][u] = *(const long2v*)(brow + t * 4096 + h * 32 + u * 16);
            }
        }
        #pragma unroll
        for (int u = 0; u < 2; ++u) {
            #pragma unroll
            for (int p = 0; p < 2; ++p) {       // s = 4h + 2u + p
                long a0 = av[0][u][p], a1 = av[1][u][p];
                long b0 = bv[0][u][p], b1 = bv[1][u][p];
                acc[0][0] = __builtin_amdgcn_mfma_f32_32x32x16_fp8_fp8(a0, b0, acc[0][0], 0, 0, 0);
                acc[0][1] = __builtin_amdgcn_mfma_f32_32x32x16_fp8_fp8(a0, b1, acc[0][1], 0, 0, 0);
                acc[1][0] = __builtin_amdgcn_mfma_f32_32x32x16_fp8_fp8(a1, b0, acc[1][0], 0, 0, 0);
                acc[1][1] = __builtin_amdgcn_mfma_f32_32x32x16_fp8_fp8(a1, b1, acc[1][1], 0, 0, 0);
            }
        }
    }

    // Epilogue: s += sqrt(max(xx+yy-2c, 0)), fast sqrt, 2-way split chain.
    float s0 = 0.0f, s1 = 0.0f;
    #pragma unroll
    for (int tr = 0; tr < 2; ++tr) {
        float xv[16];
        #pragma unroll
        for (int r = 0; r < 16; ++r) {
            int ml = wr * 64 + tr * 32 + (r & 3) + 8 * (r >> 2) + 4 * fh;
            xv[r] = xxl[ml];
        }
        #pragma unroll
        for (int tc = 0; tc < 2; ++tc) {
            float yv = yyl[wc * 64 + tc * 32 + lm];
            #pragma unroll
            for (int r = 0; r < 16; ++r) {
                float d2 = fmaf(-2.0f, acc[tr][tc][r], xv[r] + yv);
                float d = __builtin_amdgcn_sqrtf(fmaxf(d2, 0.0f));
                if (r & 1) s1 += d; else s0 += d;
            }
        }
    }
    float s = s0 + s1;

    // Diagonal correction: only 64 of 4096 blocks, only waves with wr==wc.
    if (bx == by && wr == wc) {
        #pragma unroll
        for (int t = 0; t < 2; ++t) {
            #pragma unroll
            for (int r = 0; r < 16; ++r) {
                int row = (r & 3) + 8 * (r >> 2) + 4 * fh;
                if (row == lm) {
                    int idx = wr * 64 + t * 32 + row;
                    float d2 = fmaf(-2.0f, acc[t][t][r], xxl[idx] + yyl[idx]);
                    s -= 2.0f * __builtin_amdgcn_sqrtf(fmaxf(d2, 0.0f));
                }
            }
        }
    }

    #pragma unroll
    for (int off = 32; off > 0; off >>= 1) s += __shfl_down(s, off);
    if (lane == 0) wsum[wid] = s;
    __syncthreads();
    if (tid == 0) partials[by * 64 + bx] = wsum[0] + wsum[1] + wsum[2] + wsum[3];
}

__global__ __launch_bounds__(256) void reduce_kernel(const float* __restrict__ partials,
                                                     float* __restrict__ out) {
    __shared__ float wsum[4];
    float s = 0.0f;
    for (int i = threadIdx.x; i < 4096; i += 256) s += partials[i];
    #pragma unroll
    for (int off = 32; off > 0; off >>= 1) s += __shfl_down(s, off);
    int lane = threadIdx.x & 63, wid = threadIdx.x >> 6;
    if (lane == 0) wsum[wid] = s;
    __syncthreads();
    if (threadIdx.x == 0)
        out[0] = (wsum[0] + wsum[1] + wsum[2] + wsum[3]) * (0.1f / 8192.0f);
}

extern "C" void kernel_launch(void* const* d_in, const int* in_sizes, int n_in,
                              void* d_out, int out_size, void* d_ws, size_t ws_size,
                              hipStream_t stream) {
    const float* output = (const float*)d_in[0];
    const float* target = (const float*)d_in[1];

    uint8_t* ws = (uint8_t*)d_ws;
    uint8_t* ak      = ws;                                    // A fp8 (1MB) + B fp8 (1MB)
    float*   xxyy    = (float*)(ws + 2u * 1024u * 1024u);     // xx (32KB) + yy (32KB)
    float*   partial = (float*)(ws + 2u * 1024u * 1024u + 64u * 1024u); // 4096 floats

    prep_kernel<<<dim3(512, 2), 256, 0, stream>>>(output, target, ak, xxyy);
    dist_kernel<<<dim3(64, 64), 256, 0, stream>>>(ak, ak + (1u << 20),
                                                  xxyy, xxyy + BDIM, partial);
    reduce_kernel<<<1, 256, 0, stream>>>(partial, (float*)d_out);
}